// Round 3
// baseline (674.189 us; speedup 1.0000x reference)
//
#include <hip/hip_runtime.h>
#include <stdint.h>

// Viterbi CRF decode: B=1024, T=1024, N=34 (32 tags + START=32 + END=33)
// One wave (64 lanes) = one batch. Lane j (<34) owns target row j.
// Score vector rebroadcast per step via v_readlane (no LDS, no barriers).
// Backpointers written straight to LDS; backtrack runs in-kernel on LDS.
#define BB 1024
#define TT 1024
#define NN 34
#define NEGV -6969.0f

__device__ __forceinline__ float rdlane_f(float v, int l) {
    return __int_as_float(__builtin_amdgcn_readlane(__float_as_int(v), l));
}

__global__ __launch_bounds__(64) void viterbi_wave(
        const float* __restrict__ feat,   // [B,T,34]
        const float* __restrict__ trans,  // [34,34]
        float* __restrict__ out)          // best[B] ++ path[B,T+1]
{
    __shared__ unsigned char bp[TT * NN];   // 34816 B backpointers (this batch)
    __shared__ unsigned char Fm[16 * NN];   // chunk maps

    const int lane = threadIdx.x;
    const int bg   = blockIdx.x;
    const int jc   = (lane < NN) ? lane : (NN - 1);   // clamp idle lanes

    // my transition row (constant over t) + end-transition element
    float tr[NN];
#pragma unroll
    for (int k = 0; k < NN; ++k) tr[k] = trans[jc * NN + k];
    const float trE = trans[33 * NN + jc];

    // feature pointer for my row; 4-deep prefetch ring
    const float* fp = feat + (size_t)bg * TT * NN + jc;
    float fr0 = fp[0 * NN], fr1 = fp[1 * NN], fr2 = fp[2 * NN], fr3 = fp[3 * NN];

    // replicated score vector (uniform across lanes; lives in SGPRs after
    // the first readlane broadcast)
    float sk[NN];
#pragma unroll
    for (int k = 0; k < NN; ++k) sk[k] = (k == 32) ? 0.0f : NEGV;

    float m = NEGV;   // lane j's current score
    int tbase = 0;    // t*NN byte offset into bp

    auto vstep = [&](float f) {
        // exact reference fp order: (s[k] + f[j]) + tr[j][k]
        float vv[NN];
#pragma unroll
        for (int k = 0; k < NN; ++k) vv[k] = (sk[k] + f) + tr[k];

        // max tree (depth ~6; compiler folds pairs into v_max3_f32)
        float t0[17];
#pragma unroll
        for (int k = 0; k < 17; ++k) t0[k] = fmaxf(vv[2 * k], vv[2 * k + 1]);
        float t1[8];
#pragma unroll
        for (int k = 0; k < 8; ++k) t1[k] = fmaxf(t0[2 * k], t0[2 * k + 1]);
        float t2a = fmaxf(fmaxf(t1[0], t1[1]), fmaxf(t1[2], t1[3]));
        float t2b = fmaxf(fmaxf(t1[4], t1[5]), fmaxf(t1[6], t1[7]));
        float mx  = fmaxf(fmaxf(t2a, t2b), t0[16]);

        // argmax = first k attaining mx: 4 descending cmp/sel chains + min
        int am0 = 127, am1 = 127, am2 = 127, am3 = 127;
#pragma unroll
        for (int k = NN - 1; k >= 0; --k) {
            bool e = (vv[k] == mx);
            if ((k & 3) == 0) am0 = e ? k : am0;
            else if ((k & 3) == 1) am1 = e ? k : am1;
            else if ((k & 3) == 2) am2 = e ? k : am2;
            else am3 = e ? k : am3;
        }
        int am = min(min(am0, am1), min(am2, am3));

        if (lane < NN) bp[tbase + lane] = (unsigned char)am;
        tbase += NN;

        // rebroadcast new score vector (lane k -> all lanes), no LDS
#pragma unroll
        for (int k = 0; k < NN; ++k) sk[k] = rdlane_f(mx, k);
        m = mx;
    };

    // forward: 255 iters x 4 steps, prefetching t+4..t+7
    for (int n = 0; n < 255; ++n) {
        { float f = fr0; fr0 = fp[4 * NN]; vstep(f); }
        { float f = fr1; fr1 = fp[5 * NN]; vstep(f); }
        { float f = fr2; fr2 = fp[6 * NN]; vstep(f); }
        { float f = fr3; fr3 = fp[7 * NN]; vstep(f); }
        fp += 4 * NN;
    }
    vstep(fr0); vstep(fr1); vstep(fr2); vstep(fr3);

    // ---- end transition + final max/argmax (uniform in all lanes)
    float fs = m + trE;                       // lane j: s_T[j] + trans[END][j]
    float bm = rdlane_f(fs, 0);
    int bi = 0;
#pragma unroll
    for (int k = 1; k < NN; ++k) {
        float v = rdlane_f(fs, k);
        bool g = (v > bm);                    // strict >  => first index on ties
        bm = g ? v : bm;
        bi = g ? k : bi;
    }
    if (lane == 0) out[bg] = bm;

    // ---- backtrack, all on LDS (single wave: ds ops are wave-ordered)
    // level-1: 16 chunks x 34 hypotheses = 544 jobs; 9 jobs/lane, interleaved
    int cc[9], xx[9], mm[9], cb[9];
#pragma unroll
    for (int r = 0; r < 9; ++r) {
        int job = 64 * r + lane;
        if (job > 543) job = 543;
        cc[r] = job / 34;
        xx[r] = job - 34 * cc[r];
        mm[r] = xx[r];
        cb[r] = cc[r] * (64 * NN);
    }
    for (int i = 63; i >= 0; --i) {
        int ib = i * NN;
#pragma unroll
        for (int r = 0; r < 9; ++r) mm[r] = bp[cb[r] + ib + mm[r]];
    }
#pragma unroll
    for (int r = 0; r < 9; ++r) Fm[cc[r] * NN + xx[r]] = (unsigned char)mm[r];

    // level-2: serial 16-chunk scan (uniform broadcast reads)
    int e = bi;
    int myeb = (lane == 15) ? e : 0;
#pragma unroll
    for (int c2 = 15; c2 >= 1; --c2) {
        e = Fm[c2 * NN + e];
        myeb = (lane == c2 - 1) ? e : myeb;
    }

    // emit: lanes 0..15 re-chase their chunk and write the path
    float* po = out + BB + (size_t)bg * (TT + 1);
    if (lane < 16) {
        int mm2 = myeb;
        int base = lane * (64 * NN);
        for (int i = 63; i >= 0; --i) {
            mm2 = bp[base + i * NN + mm2];
            po[lane * 64 + i] = (float)mm2;
        }
    }
    if (lane == 16) po[TT] = (float)bi;
}

extern "C" void kernel_launch(void* const* d_in, const int* in_sizes, int n_in,
                              void* d_out, int out_size, void* d_ws, size_t ws_size,
                              hipStream_t stream) {
    const float* feat  = (const float*)d_in[0];   // [1024,1024,34]
    const float* trans = (const float*)d_in[1];   // [34,34]
    float* out = (float*)d_out;                   // 1024 + 1024*1025 floats

    viterbi_wave<<<BB, 64, 0, stream>>>(feat, trans, out);
}

// Round 4
// 604.758 us; speedup vs baseline: 1.1148x; 1.1148x over previous
//
#include <hip/hip_runtime.h>
#include <stdint.h>

// Viterbi CRF decode: B=1024, T=1024, N=34 (32 tags + START=32 + END=33)
// One wave = one batch (1024 waves on 1024 SIMDs). Lane j<34 owns row j.
// Per step: packed adds (v_pk_add_f32, bit-exact RN), max3 tree, exact
// first-index eq-scan, score broadcast via LDS write + b64 broadcast reads.
#define BB 1024
#define TT 1024
#define NN 34
#define NEGV -6969.0f

typedef float v2f __attribute__((ext_vector_type(2)));

__device__ __forceinline__ v2f pk_add(v2f a, v2f b) {
    v2f d;
    asm("v_pk_add_f32 %0, %1, %2" : "=v"(d) : "v"(a), "v"(b));
    return d;
}

__device__ __forceinline__ float rdlane_f(float v, int l) {
    return __int_as_float(__builtin_amdgcn_readlane(__float_as_int(v), l));
}

__global__ __launch_bounds__(64, 1) void viterbi_wave(
        const float* __restrict__ feat,   // [B,T,34]
        const float* __restrict__ trans,  // [34,34]
        float* __restrict__ out)          // best[B] ++ path[B,T+1]
{
    __shared__ unsigned char bp[TT * NN];          // 34816 B backpointers
    __shared__ __align__(16) float sc[64];         // score exchange
    __shared__ unsigned char Fm[16 * NN];          // chunk maps

    const int lane = threadIdx.x;
    const int bg   = blockIdx.x;
    const int jc   = (lane < NN) ? lane : (NN - 1);   // clamp idle lanes

    // transition row as 17 float2 pairs (constant over t)
    v2f tr2[17];
#pragma unroll
    for (int p = 0; p < 17; ++p) {
        tr2[p].x = trans[jc * NN + 2 * p];
        tr2[p].y = trans[jc * NN + 2 * p + 1];
    }
    const float trE = trans[33 * NN + jc];

    // feature pointer for my row; 4-deep prefetch ring
    const float* fp = feat + (size_t)bg * TT * NN + jc;
    float fr0 = fp[0 * NN], fr1 = fp[1 * NN], fr2 = fp[2 * NN], fr3 = fp[3 * NN];

    // replicated score vector as float2 pairs (k=32 START = 0, rest NEG)
    v2f sk2[17];
#pragma unroll
    for (int p = 0; p < 17; ++p) { sk2[p].x = NEGV; sk2[p].y = NEGV; }
    sk2[16].x = 0.0f;

    float m = NEGV;   // lane j's current score
    int tbase = 0;

    auto vstep = [&](float f) {
        // exact reference fp order: (s[k] + f[j]) + tr[j][k], packed RN adds
        v2f f2; f2.x = f; f2.y = f;
        v2f q[17];
#pragma unroll
        for (int p = 0; p < 17; ++p) q[p] = pk_add(pk_add(sk2[p], f2), tr2[p]);

        // pair maxes then tree (exact; compiler folds to v_max3_f32)
        float pm[17];
#pragma unroll
        for (int p = 0; p < 17; ++p) pm[p] = fmaxf(q[p].x, q[p].y);
        float u0 = fmaxf(fmaxf(pm[0], pm[1]),   fmaxf(pm[2], pm[3]));
        float u1 = fmaxf(fmaxf(pm[4], pm[5]),   fmaxf(pm[6], pm[7]));
        float u2 = fmaxf(fmaxf(pm[8], pm[9]),   fmaxf(pm[10], pm[11]));
        float u3 = fmaxf(fmaxf(pm[12], pm[13]), fmaxf(pm[14], pm[15]));
        float mx = fmaxf(fmaxf(fmaxf(u0, u1), fmaxf(u2, u3)), pm[16]);

        // broadcast: issue LDS write+reads now; latency hides under eq-scan
        sc[lane] = mx;
#pragma unroll
        for (int p = 0; p < 17; ++p) sk2[p] = *(const v2f*)&sc[2 * p];

        // argmax = first k attaining mx: 4 descending cmp/sel chains + min
        int am0 = 127, am1 = 127, am2 = 127, am3 = 127;
#pragma unroll
        for (int p = 16; p >= 0; --p) {
            int k0 = 2 * p, k1 = 2 * p + 1;
            bool e1 = (q[p].y == mx);
            if ((k1 & 3) == 0) am0 = e1 ? k1 : am0;
            else if ((k1 & 3) == 1) am1 = e1 ? k1 : am1;
            else if ((k1 & 3) == 2) am2 = e1 ? k1 : am2;
            else am3 = e1 ? k1 : am3;
            bool e0 = (q[p].x == mx);
            if ((k0 & 3) == 0) am0 = e0 ? k0 : am0;
            else if ((k0 & 3) == 1) am1 = e0 ? k0 : am1;
            else if ((k0 & 3) == 2) am2 = e0 ? k0 : am2;
            else am3 = e0 ? k0 : am3;
        }
        int am = min(min(am0, am1), min(am2, am3));

        if (lane < NN) bp[tbase + lane] = (unsigned char)am;
        tbase += NN;
        m = mx;
    };

    // forward: 255 iters x 4 steps, prefetching t+4..t+7
    for (int n = 0; n < 255; ++n) {
        { float f = fr0; fr0 = fp[4 * NN]; vstep(f); }
        { float f = fr1; fr1 = fp[5 * NN]; vstep(f); }
        { float f = fr2; fr2 = fp[6 * NN]; vstep(f); }
        { float f = fr3; fr3 = fp[7 * NN]; vstep(f); }
        fp += 4 * NN;
    }
    vstep(fr0); vstep(fr1); vstep(fr2); vstep(fr3);

    // ---- end transition + final max/argmax (uniform across lanes)
    float fs = m + trE;
    float bm = rdlane_f(fs, 0);
    int bi = 0;
#pragma unroll
    for (int k = 1; k < NN; ++k) {
        float v = rdlane_f(fs, k);
        bool g = (v > bm);                 // strict >  => first index on ties
        bm = g ? v : bm;
        bi = g ? k : bi;
    }
    if (lane == 0) out[bg] = bm;

    // ---- backtrack on LDS (single wave: ds ops are wave-ordered)
    // level-1: 16 chunks x 34 hypotheses = 544 jobs; 9 jobs/lane
    int cc[9], xx[9], mm[9], cb[9];
#pragma unroll
    for (int r = 0; r < 9; ++r) {
        int job = 64 * r + lane;
        if (job > 543) job = 543;
        cc[r] = job / 34;
        xx[r] = job - 34 * cc[r];
        mm[r] = xx[r];
        cb[r] = cc[r] * (64 * NN);
    }
    for (int i = 63; i >= 0; --i) {
        int ib = i * NN;
#pragma unroll
        for (int r = 0; r < 9; ++r) mm[r] = bp[cb[r] + ib + mm[r]];
    }
#pragma unroll
    for (int r = 0; r < 9; ++r) Fm[cc[r] * NN + xx[r]] = (unsigned char)mm[r];

    // level-2: serial 16-chunk scan
    int e = bi;
    int myeb = (lane == 15) ? e : 0;
#pragma unroll
    for (int c2 = 15; c2 >= 1; --c2) {
        e = Fm[c2 * NN + e];
        myeb = (lane == c2 - 1) ? e : myeb;
    }

    // emit: lanes 0..15 re-chase their chunk and write the path
    float* po = out + BB + (size_t)bg * (TT + 1);
    if (lane < 16) {
        int mm2 = myeb;
        int base = lane * (64 * NN);
        for (int i = 63; i >= 0; --i) {
            mm2 = bp[base + i * NN + mm2];
            po[lane * 64 + i] = (float)mm2;
        }
    }
    if (lane == 16) po[TT] = (float)bi;
}

extern "C" void kernel_launch(void* const* d_in, const int* in_sizes, int n_in,
                              void* d_out, int out_size, void* d_ws, size_t ws_size,
                              hipStream_t stream) {
    const float* feat  = (const float*)d_in[0];   // [1024,1024,34]
    const float* trans = (const float*)d_in[1];   // [34,34]
    float* out = (float*)d_out;                   // 1024 + 1024*1025 floats

    viterbi_wave<<<BB, 64, 0, stream>>>(feat, trans, out);
}